// Round 5
// baseline (128.791 us; speedup 1.0000x reference)
//
#include <hip/hip_runtime.h>
#include <math.h>

#define NB 1024
#define NN 512
#define ND 128
#define CHUNKS 4                 // K1 chunks per batch
#define ROWS_PER_CHUNK (NN / CHUNKS)   // 128

// ws layout (bytes):
//   wsg : [NB*CHUNKS][ND] f32 at 0          (2 MiB)  plain column sums
//   wsv : [NB*CHUNKS][ND] f32 at 2 MiB      (2 MiB)  visited-weighted sums
//   wsc : [NB*CHUNKS]     f32 at 4 MiB      (16 KiB) visited counts
//   wsqp: [NB][ND]        f32 at 4 MiB+64K  (512 KiB) q' vectors
#define WSG_OFF  0
#define WSV_OFF  (2u * 1024u * 1024u)
#define WSC_OFF  (4u * 1024u * 1024u)
#define WSQP_OFF (4u * 1024u * 1024u + 65536u)

// ---------------------------------------------------------------------------
// K1: per-(batch,chunk) column sums of node_emb (plain + visited-weighted)
// ---------------------------------------------------------------------------
__global__ __launch_bounds__(256) void k1_reduce(
    const float* __restrict__ node_emb,
    const int* __restrict__ visited,
    float* __restrict__ wsg,
    float* __restrict__ wsv,
    float* __restrict__ wsc)
{
    const int bid  = blockIdx.x;          // 0..NB*CHUNKS-1
    const int b    = bid >> 2;
    const int c    = bid & 3;
    const int t    = threadIdx.x;         // 0..255
    const int l5   = t & 31;
    const int strm = t >> 5;              // 0..7, 16 rows each

    __shared__ float4 sg[8][32];
    __shared__ float4 sv[8][32];
    __shared__ float  svisf[ROWS_PER_CHUNK];
    __shared__ float  sredc[2];

    if (t < ROWS_PER_CHUNK)
        svisf[t] = visited[(size_t)b * NN + c * ROWS_PER_CHUNK + t] ? 1.0f : 0.0f;
    __syncthreads();

    const float* base = node_emb + (size_t)b * NN * ND
                      + (size_t)c * ROWS_PER_CHUNK * ND
                      + (size_t)strm * 16 * ND + l5 * 4;
    float4 g = make_float4(0.f, 0.f, 0.f, 0.f);
    float4 v = make_float4(0.f, 0.f, 0.f, 0.f);
#pragma unroll
    for (int k = 0; k < 16; ++k) {
        float4 x = *reinterpret_cast<const float4*>(base + (size_t)k * ND);
        float vf = svisf[strm * 16 + k];
        g.x += x.x; g.y += x.y; g.z += x.z; g.w += x.w;
        v.x = fmaf(vf, x.x, v.x); v.y = fmaf(vf, x.y, v.y);
        v.z = fmaf(vf, x.z, v.z); v.w = fmaf(vf, x.w, v.w);
    }
    sg[strm][l5] = g;
    sv[strm][l5] = v;

    // visited count partial (first two waves hold the 128 flags)
    float vc = (t < ROWS_PER_CHUNK) ? svisf[t] : 0.0f;
#pragma unroll
    for (int off = 32; off >= 1; off >>= 1) vc += __shfl_xor(vc, off);
    if (t < ROWS_PER_CHUNK && (t & 63) == 0) sredc[t >> 6] = vc;
    __syncthreads();

    if (t < 32) {
        float4 G = sg[0][t], V = sv[0][t];
#pragma unroll
        for (int j = 1; j < 8; ++j) {
            float4 a = sg[j][t], d = sv[j][t];
            G.x += a.x; G.y += a.y; G.z += a.z; G.w += a.w;
            V.x += d.x; V.y += d.y; V.z += d.z; V.w += d.w;
        }
        reinterpret_cast<float4*>(wsg + (size_t)bid * ND)[t] = G;
        reinterpret_cast<float4*>(wsv + (size_t)bid * ND)[t] = V;
    }
    if (t == 0) wsc[bid] = sredc[0] + sredc[1];
}

// ---------------------------------------------------------------------------
// K2: combine partials -> graph mean / h_visited; build q then q' = W_key q
// ---------------------------------------------------------------------------
__global__ __launch_bounds__(256) void k2_query(
    const float* __restrict__ node_emb,
    const float* __restrict__ W_last,
    const float* __restrict__ W_first,
    const float* __restrict__ W_graph,
    const float* __restrict__ W_visited,
    const float* __restrict__ W_key,
    const float* __restrict__ W_state,
    const float* __restrict__ b_state,
    const float* __restrict__ current_time,
    const float* __restrict__ used_capacity,
    const float* __restrict__ vehicle_capacity,
    const int* __restrict__ current_node,
    const int* __restrict__ previous_action,
    const int* __restrict__ first_node,
    const int* __restrict__ step_i,
    const float* __restrict__ wsg,
    const float* __restrict__ wsv,
    const float* __restrict__ wsc,
    float* __restrict__ wsqp)
{
    const int b  = blockIdx.x;
    const int t  = threadIdx.x;   // 0..255
    const int l5 = t & 31;
    const int strm = t >> 5;      // 0..7

    __shared__ float smean[ND];
    __shared__ float svis[ND];
    __shared__ float shcur[ND];
    __shared__ float shfirst[ND];
    __shared__ float qs[ND];
    __shared__ float part[2][ND];
    __shared__ float s_scal[4];

    int cur  = current_node[b];
    int prev = previous_action[b];
    int fn   = first_node[b];
    if (prev == 0 && cur != 0) fn = cur;
    if (cur == 0) fn = 0;

    const float* nb = node_emb + (size_t)b * NN * ND;

    if (t < ND) {
        const float* g0 = wsg + (size_t)b * CHUNKS * ND;
        const float* v0 = wsv + (size_t)b * CHUNKS * ND;
        float g = g0[t] + g0[ND + t] + g0[2 * ND + t] + g0[3 * ND + t];
        float v = v0[t] + v0[ND + t] + v0[2 * ND + t] + v0[3 * ND + t];
        smean[t] = g * (1.0f / (float)NN);
        svis[t]  = v;
        shcur[t]   = nb[(size_t)cur * ND + t];
        shfirst[t] = nb[(size_t)fn  * ND + t];
    }
    if (t == 0) {
        float c = wsc[b * CHUNKS] + wsc[b * CHUNKS + 1]
                + wsc[b * CHUNKS + 2] + wsc[b * CHUNKS + 3];
        s_scal[0] = 1.0f / fmaxf(c, 1.0f);
        s_scal[1] = vehicle_capacity[b] - used_capacity[b];
        s_scal[2] = current_time[b] * (1.0f / 1440.0f);
        s_scal[3] = (float)step_i[b] * (1.0f / (2.0f * (float)NN));
    }
    __syncthreads();

    // q[e]: two groups of 128 threads, 64 d-terms each, 4 independent chains
    {
        const int e  = t & 127;
        const int g2 = t >> 7;       // 0..1
        const int d0 = g2 * 64;
        float a0 = 0.f, a1 = 0.f, a2 = 0.f, a3 = 0.f;
#pragma unroll 8
        for (int dd = 0; dd < 64; ++dd) {
            int d = d0 + dd;
            a0 = fmaf(shcur[d],   W_last[d * ND + e],    a0);
            a1 = fmaf(shfirst[d], W_first[d * ND + e],   a1);
            a2 = fmaf(smean[d],   W_graph[d * ND + e],   a2);
            a3 = fmaf(svis[d],    W_visited[d * ND + e], a3);
        }
        float p = a0 + a1 + a2 + s_scal[0] * a3;
        if (g2 == 0) {
            p += b_state[e]
               + s_scal[1] * W_state[e]
               + s_scal[2] * W_state[ND + e]
               + s_scal[3] * W_state[2 * ND + e];
        }
        part[g2][e] = p;
    }
    __syncthreads();

    if (t < ND) qs[t] = part[0][t] + part[1][t];
    __syncthreads();

    // q'[d] = (W_key @ q)[d] / sqrt(D)
    {
        float4 qv = *reinterpret_cast<const float4*>(&qs[l5 * 4]);
#pragma unroll
        for (int it = 0; it < 16; ++it) {
            int d = it * 8 + strm;
            float4 wk = *reinterpret_cast<const float4*>(W_key + (size_t)d * ND + l5 * 4);
            float s = wk.x * qv.x + wk.y * qv.y + wk.z * qv.z + wk.w * qv.w;
            s += __shfl_xor(s, 16); s += __shfl_xor(s, 8);
            s += __shfl_xor(s, 4);  s += __shfl_xor(s, 2); s += __shfl_xor(s, 1);
            if (l5 == 0) wsqp[(size_t)b * ND + d] = s * 0.08838834764831845f;
        }
    }
}

// ---------------------------------------------------------------------------
// K3: scores = q'.node_emb rows, travel adjust, tanh clip, mask, log_softmax
// ---------------------------------------------------------------------------
__global__ __launch_bounds__(512) void k3_score(
    const float* __restrict__ node_emb,
    const float* __restrict__ ttm,
    const int* __restrict__ current_node,
    const int* __restrict__ action_mask,
    const int* __restrict__ h3_indices,
    const float* __restrict__ wsqp,
    float* __restrict__ out)
{
    const int b    = blockIdx.x;
    const int t    = threadIdx.x;   // 0..511
    const int wave = t >> 6;
    const int lane = t & 63;
    const int l5   = t & 31;
    const int strm = t >> 5;        // 0..15

    __shared__ float scores[NN];
    __shared__ float sred[16];

    const float* nb = node_emb + (size_t)b * NN * ND;
    float4 qv = *reinterpret_cast<const float4*>(wsqp + (size_t)b * ND + l5 * 4);

#pragma unroll 4
    for (int it = 0; it < 32; ++it) {
        int n = it * 16 + strm;
        float4 x = *reinterpret_cast<const float4*>(nb + (size_t)n * ND + l5 * 4);
        float s = x.x * qv.x + x.y * qv.y + x.z * qv.z + x.w * qv.w;
        s += __shfl_xor(s, 16); s += __shfl_xor(s, 8);
        s += __shfl_xor(s, 4);  s += __shfl_xor(s, 2); s += __shfl_xor(s, 1);
        if (l5 == 0) scores[n] = s;
    }
    __syncthreads();

    const int    cur    = current_node[b];
    const int    cur_h3 = h3_indices[(size_t)b * NN + cur];
    const float* trow   = ttm + (size_t)cur_h3 * NN;
    const float  tscale = 1.0f / (1440.0f * 1.4142135623730951f);

    float s1 = scores[t];
    int   h1 = h3_indices[(size_t)b * NN + t];
    s1 -= trow[h1] * tscale;
    s1 = 10.0f * tanhf(s1 * 0.1f);
    if (!action_mask[(size_t)b * NN + t]) s1 = -1e8f;

    float m = s1;
#pragma unroll
    for (int off = 32; off >= 1; off >>= 1) m = fmaxf(m, __shfl_xor(m, off));
    if (lane == 0) sred[wave] = m;
    __syncthreads();
    float bm = fmaxf(fmaxf(fmaxf(sred[0], sred[1]), fmaxf(sred[2], sred[3])),
                     fmaxf(fmaxf(sred[4], sred[5]), fmaxf(sred[6], sred[7])));

    float es = expf(s1 - bm);
#pragma unroll
    for (int off = 32; off >= 1; off >>= 1) es += __shfl_xor(es, off);
    if (lane == 0) sred[8 + wave] = es;
    __syncthreads();
    float lse = bm + logf(sred[8] + sred[9] + sred[10] + sred[11]
                        + sred[12] + sred[13] + sred[14] + sred[15]);

    out[(size_t)b * NN + t] = s1 - lse;
}

extern "C" void kernel_launch(void* const* d_in, const int* in_sizes, int n_in,
                              void* d_out, int out_size, void* d_ws, size_t ws_size,
                              hipStream_t stream) {
    (void)in_sizes; (void)n_in; (void)ws_size; (void)out_size;
    const float* node_emb   = (const float*)d_in[0];
    const float* W_last     = (const float*)d_in[1];
    const float* W_first    = (const float*)d_in[2];
    const float* W_graph    = (const float*)d_in[3];
    const float* W_visited  = (const float*)d_in[4];
    const float* W_key      = (const float*)d_in[5];
    const float* W_state    = (const float*)d_in[6];
    const float* b_state    = (const float*)d_in[7];
    const float* cur_time   = (const float*)d_in[8];
    const float* used_cap   = (const float*)d_in[9];
    const float* veh_cap    = (const float*)d_in[10];
    const float* ttm        = (const float*)d_in[11];
    const int*   cur_node   = (const int*)d_in[12];
    const int*   prev_act   = (const int*)d_in[13];
    const int*   first_node = (const int*)d_in[14];
    const int*   visited    = (const int*)d_in[15];
    const int*   action_msk = (const int*)d_in[16];
    const int*   step_i     = (const int*)d_in[17];
    const int*   h3         = (const int*)d_in[18];
    float*       out        = (float*)d_out;

    char* ws = (char*)d_ws;
    float* wsg  = (float*)(ws + WSG_OFF);
    float* wsv  = (float*)(ws + WSV_OFF);
    float* wsc  = (float*)(ws + WSC_OFF);
    float* wsqp = (float*)(ws + WSQP_OFF);

    k1_reduce<<<dim3(NB * CHUNKS), dim3(256), 0, stream>>>(
        node_emb, visited, wsg, wsv, wsc);
    k2_query<<<dim3(NB), dim3(256), 0, stream>>>(
        node_emb, W_last, W_first, W_graph, W_visited, W_key, W_state, b_state,
        cur_time, used_cap, veh_cap, cur_node, prev_act, first_node, step_i,
        wsg, wsv, wsc, wsqp);
    k3_score<<<dim3(NB), dim3(512), 0, stream>>>(
        node_emb, ttm, cur_node, action_msk, h3, wsqp, out);
}